// Round 1
// baseline (390.930 us; speedup 1.0000x reference)
//
#include <hip/hip_runtime.h>
#include <float.h>

#define NSTATES 65536
#define DIM 512
#define K1_BLOCKS 512
#define K1_THREADS 256
#define WPB 4                                   // waves per block
#define ROWS_PER_BLOCK (NSTATES / K1_BLOCKS)    // 128
#define ROWS_PER_WAVE (ROWS_PER_BLOCK / WPB)    // 32
#define K2_THREADS 512

// Kernel 1: one streaming pass over on_states [N, D, 2].
// Each wave owns ROWS_PER_WAVE consecutive rows. Per row: coalesced float4
// loads (4 KB row), squared-W2 distance via wave butterfly reduce, then an
// online-softmin update of (m, s, q[512]) kept in registers (q distributed
// 8 dims/lane). Waves merge through LDS -> one partial per block.
__global__ __launch_bounds__(K1_THREADS) void k_dist(
    const float* __restrict__ imu, const float* __restrict__ isig,
    const float* __restrict__ st, float* __restrict__ dists,
    float* __restrict__ ws_q, float* __restrict__ ws_m, float* __restrict__ ws_s)
{
    const int lane = threadIdx.x & 63;
    const int wid  = threadIdx.x >> 6;

    // lane's 8 dims: {128k + 2*lane, 128k + 2*lane + 1} for k=0..3
    float im[8], isg[8];
    #pragma unroll
    for (int k = 0; k < 4; ++k) {
        const int d0 = 128 * k + 2 * lane;
        im[2*k]    = imu[d0];   im[2*k+1]  = imu[d0 + 1];
        isg[2*k]   = isig[d0];  isg[2*k+1] = isig[d0 + 1];
    }

    float m = FLT_MAX, s = 0.f;
    float q[8] = {0.f, 0.f, 0.f, 0.f, 0.f, 0.f, 0.f, 0.f};

    const int row0 = blockIdx.x * ROWS_PER_BLOCK + wid * ROWS_PER_WAVE;
    for (int r = 0; r < ROWS_PER_WAVE; ++r) {
        const int n = row0 + r;
        const float4* p = reinterpret_cast<const float4*>(st + (size_t)n * (2 * DIM));
        // 4 coalesced 1-KB segments; v.x=mu[d0], v.y=sig[d0], v.z=mu[d0+1], v.w=sig[d0+1]
        const float4 v0 = p[lane];
        const float4 v1 = p[64  + lane];
        const float4 v2 = p[128 + lane];
        const float4 v3 = p[192 + lane];

        float d = 0.f, a, b;
        a = v0.x - im[0]; b = v0.y - isg[0]; d += a*a + b*b;
        a = v0.z - im[1]; b = v0.w - isg[1]; d += a*a + b*b;
        a = v1.x - im[2]; b = v1.y - isg[2]; d += a*a + b*b;
        a = v1.z - im[3]; b = v1.w - isg[3]; d += a*a + b*b;
        a = v2.x - im[4]; b = v2.y - isg[4]; d += a*a + b*b;
        a = v2.z - im[5]; b = v2.w - isg[5]; d += a*a + b*b;
        a = v3.x - im[6]; b = v3.y - isg[6]; d += a*a + b*b;
        a = v3.z - im[7]; b = v3.w - isg[7]; d += a*a + b*b;

        #pragma unroll
        for (int off = 32; off >= 1; off >>= 1) d += __shfl_xor(d, off, 64);

        if (lane == 0) dists[n] = d;

        // online softmin: weights exp(-(d_n - m)), rescale on new min
        const float mn   = fminf(m, d);
        const float cold = __expf(mn - m);   // <= 1, rescales old accum
        const float w    = __expf(mn - d);   // weight of this row
        s = s * cold + w;
        q[0] = q[0] * cold + w * v0.x;  q[1] = q[1] * cold + w * v0.z;
        q[2] = q[2] * cold + w * v1.x;  q[3] = q[3] * cold + w * v1.z;
        q[4] = q[4] * cold + w * v2.x;  q[5] = q[5] * cold + w * v2.z;
        q[6] = q[6] * cold + w * v3.x;  q[7] = q[7] * cold + w * v3.z;
        m = mn;
    }

    // merge the block's WPB wave-partials via LDS
    __shared__ float lq[WPB][DIM];
    __shared__ float lm[WPB], ls[WPB];
    #pragma unroll
    for (int k = 0; k < 4; ++k) {
        const int d0 = 128 * k + 2 * lane;
        lq[wid][d0]     = q[2*k];
        lq[wid][d0 + 1] = q[2*k + 1];
    }
    if (lane == 0) { lm[wid] = m; ls[wid] = s; }
    __syncthreads();

    const int t = threadIdx.x;           // 256 threads handle dims t, t+256
    const float M = fminf(fminf(lm[0], lm[1]), fminf(lm[2], lm[3]));
    float qa = 0.f, qb = 0.f;
    #pragma unroll
    for (int w2 = 0; w2 < WPB; ++w2) {
        const float f = __expf(M - lm[w2]);
        qa += lq[w2][t]       * f;
        qb += lq[w2][t + 256] * f;
    }
    ws_q[blockIdx.x * DIM + t]       = qa;
    ws_q[blockIdx.x * DIM + t + 256] = qb;
    if (t == 0) {
        float stot = 0.f;
        #pragma unroll
        for (int w2 = 0; w2 < WPB; ++w2) stot += ls[w2] * __expf(M - lm[w2]);
        ws_m[blockIdx.x] = M;
        ws_s[blockIdx.x] = stot;
    }
}

// Kernel 2: merge K1_BLOCKS partials, produce quantised + losses.
__global__ __launch_bounds__(K2_THREADS) void k_final(
    const float* __restrict__ imu,
    const float* __restrict__ ws_q, const float* __restrict__ ws_m,
    const float* __restrict__ ws_s, float* __restrict__ out)
{
    __shared__ float f_sh[K1_BLOCKS];
    __shared__ float red[8];
    __shared__ float Msh, Ssh;
    const int t = threadIdx.x;
    const int lane = t & 63, wid = t >> 6;

    // global min of block mins (K1_BLOCKS == K2_THREADS == 512)
    float mv = ws_m[t];
    #pragma unroll
    for (int off = 32; off >= 1; off >>= 1) mv = fminf(mv, __shfl_xor(mv, off, 64));
    if (lane == 0) red[wid] = mv;
    __syncthreads();
    if (t == 0) {
        float x = red[0];
        #pragma unroll
        for (int i = 1; i < 8; ++i) x = fminf(x, red[i]);
        Msh = x;
    }
    __syncthreads();
    const float M = Msh;

    // per-block rescale factors + global denominator
    const float f = __expf(M - ws_m[t]);
    f_sh[t] = f;
    float sp = ws_s[t] * f;
    #pragma unroll
    for (int off = 32; off >= 1; off >>= 1) sp += __shfl_xor(sp, off, 64);
    __syncthreads();                       // red[] reuse guard
    if (lane == 0) red[wid] = sp;
    __syncthreads();
    if (t == 0) {
        float x = 0.f;
        #pragma unroll
        for (int i = 0; i < 8; ++i) x += red[i];
        Ssh = x;
    }
    __syncthreads();
    const float S = Ssh;

    // q[t] = sum_b ws_q[b*DIM + t] * f[b]   (coalesced across t)
    float qa = 0.f;
    #pragma unroll 8
    for (int b = 0; b < K1_BLOCKS; ++b) qa += ws_q[b * DIM + t] * f_sh[b];

    const float quant = qa / S;
    out[t] = quant;                        // quantised [0..511]

    // losses: forward values of loss_enc and loss_ref are identical
    const float diff = quant - imu[t];
    float e = diff * diff;
    #pragma unroll
    for (int off = 32; off >= 1; off >>= 1) e += __shfl_xor(e, off, 64);
    __syncthreads();
    if (lane == 0) red[wid] = e;
    __syncthreads();
    if (t == 0) {
        float x = 0.f;
        #pragma unroll
        for (int i = 0; i < 8; ++i) x += red[i];
        x *= (1.0f / DIM);
        out[DIM]     = x;                  // loss_enc
        out[DIM + 1] = x;                  // loss_ref
    }
}

extern "C" void kernel_launch(void* const* d_in, const int* in_sizes, int n_in,
                              void* d_out, int out_size, void* d_ws, size_t ws_size,
                              hipStream_t stream) {
    const float* imu  = (const float*)d_in[0];
    const float* isig = (const float*)d_in[1];
    const float* st   = (const float*)d_in[2];
    float* out = (float*)d_out;
    float* ws  = (float*)d_ws;

    float* ws_q = ws;                       // [K1_BLOCKS][DIM]
    float* ws_m = ws_q + K1_BLOCKS * DIM;   // [K1_BLOCKS]
    float* ws_s = ws_m + K1_BLOCKS;         // [K1_BLOCKS]

    // out layout: quantised [0..511], loss_enc [512], loss_ref [513], dists [514..]
    k_dist<<<K1_BLOCKS, K1_THREADS, 0, stream>>>(imu, isig, st,
                                                 out + DIM + 2, ws_q, ws_m, ws_s);
    k_final<<<1, K2_THREADS, 0, stream>>>(imu, ws_q, ws_m, ws_s, out);
}

// Round 5
// 368.764 us; speedup vs baseline: 1.0601x; 1.0601x over previous
//
#include <hip/hip_runtime.h>
#include <float.h>

#define NSTATES 65536
#define DIM 512
#define K1_BLOCKS 512
#define K1_THREADS 512
#define WPB 8                                   // waves per block
#define ROWS_PER_BLOCK (NSTATES / K1_BLOCKS)    // 128
#define ROWS_PER_WAVE (ROWS_PER_BLOCK / WPB)    // 16
#define K2_THREADS 512

// native clang vector (HIP's float4 is a class — rejected by the builtin)
typedef float f4 __attribute__((ext_vector_type(4)));
#define NTL(addr) __builtin_nontemporal_load(addr)

// Kernel 1: one streaming pass over on_states [N, D, 2].
// 512 blocks x 8 waves (16 waves/CU = 4/SIMD). Each wave owns 16 consecutive
// rows, processed 2 at a time with a manual prefetch pipeline: rows r+2,r+3
// are issued before rows r,r+1 are reduced, so ~8 KB/wave stays in flight
// across the shfl/exp dependency chain. Online softmin keeps (m, s, q[512])
// in registers (8 dims/lane).
__global__ __launch_bounds__(K1_THREADS, 4) void k_dist(
    const float* __restrict__ imu, const float* __restrict__ isig,
    const float* __restrict__ st, float* __restrict__ dists,
    float* __restrict__ ws_q, float* __restrict__ ws_m, float* __restrict__ ws_s)
{
    const int lane = threadIdx.x & 63;
    const int wid  = threadIdx.x >> 6;

    // lane's 8 dims: {128k + 2*lane, 128k + 2*lane + 1} for k=0..3
    float im[8], isg[8];
    #pragma unroll
    for (int k = 0; k < 4; ++k) {
        const int d0 = 128 * k + 2 * lane;
        im[2*k]    = imu[d0];   im[2*k+1]  = imu[d0 + 1];
        isg[2*k]   = isig[d0];  isg[2*k+1] = isig[d0 + 1];
    }

    float m = FLT_MAX, s = 0.f;
    float q[8] = {0.f, 0.f, 0.f, 0.f, 0.f, 0.f, 0.f, 0.f};

    const int row0 = blockIdx.x * ROWS_PER_BLOCK + wid * ROWS_PER_WAVE;
    // base f4 pointer for this wave+lane; one row = 256 f4
    const f4* p = reinterpret_cast<const f4*>(st + (size_t)row0 * (2 * DIM)) + lane;

    // cur[0..3] = row r (4 x 1KB segments), cur[4..7] = row r+1
    f4 cur[8], nxt[8];
    #pragma unroll
    for (int k = 0; k < 4; ++k) {
        cur[k]     = NTL(p + 64 * k);
        cur[4 + k] = NTL(p + 256 + 64 * k);
    }

    #pragma unroll 1
    for (int r = 0; r < ROWS_PER_WAVE; r += 2) {
        // prefetch rows r+2, r+3 (clamped re-load of last pair on final iter:
        // no branch, no OOB)
        const int rn = (r + 2 < ROWS_PER_WAVE) ? (r + 2) : r;
        const f4* pn = p + (size_t)rn * 256;
        #pragma unroll
        for (int k = 0; k < 4; ++k) {
            nxt[k]     = NTL(pn + 64 * k);
            nxt[4 + k] = NTL(pn + 256 + 64 * k);
        }

        // distances for rows r, r+1 (two independent chains)
        float d0 = 0.f, d1 = 0.f;
        #pragma unroll
        for (int k = 0; k < 4; ++k) {
            float x, y;
            x = cur[k].x - im[2*k];       y = cur[k].y - isg[2*k];       d0 += x*x + y*y;
            x = cur[k].z - im[2*k+1];     y = cur[k].w - isg[2*k+1];     d0 += x*x + y*y;
            x = cur[4+k].x - im[2*k];     y = cur[4+k].y - isg[2*k];     d1 += x*x + y*y;
            x = cur[4+k].z - im[2*k+1];   y = cur[4+k].w - isg[2*k+1];   d1 += x*x + y*y;
        }
        #pragma unroll
        for (int off = 32; off >= 1; off >>= 1) {
            d0 += __shfl_xor(d0, off, 64);
            d1 += __shfl_xor(d1, off, 64);
        }

        const int n = row0 + r;
        if (lane == 0) {
            dists[n]     = d0;
            dists[n + 1] = d1;
        }

        // online softmin update for both rows
        const float mn   = fminf(m, fminf(d0, d1));
        const float cold = __expf(mn - m);
        const float w0   = __expf(mn - d0);
        const float w1   = __expf(mn - d1);
        s = s * cold + w0 + w1;
        #pragma unroll
        for (int k = 0; k < 4; ++k) {
            q[2*k]   = q[2*k]   * cold + w0 * cur[k].x + w1 * cur[4+k].x;
            q[2*k+1] = q[2*k+1] * cold + w0 * cur[k].z + w1 * cur[4+k].z;
        }
        m = mn;

        #pragma unroll
        for (int k = 0; k < 8; ++k) cur[k] = nxt[k];
    }

    // merge the block's WPB wave-partials via LDS
    __shared__ float lq[WPB][DIM];
    __shared__ float lm[WPB], ls[WPB];
    #pragma unroll
    for (int k = 0; k < 4; ++k) {
        const int d0 = 128 * k + 2 * lane;
        lq[wid][d0]     = q[2*k];
        lq[wid][d0 + 1] = q[2*k + 1];
    }
    if (lane == 0) { lm[wid] = m; ls[wid] = s; }
    __syncthreads();

    const int t = threadIdx.x;           // 512 threads handle dim t
    float M = lm[0];
    #pragma unroll
    for (int w2 = 1; w2 < WPB; ++w2) M = fminf(M, lm[w2]);
    float qa = 0.f;
    #pragma unroll
    for (int w2 = 0; w2 < WPB; ++w2) qa += lq[w2][t] * __expf(M - lm[w2]);
    ws_q[blockIdx.x * DIM + t] = qa;
    if (t == 0) {
        float stot = 0.f;
        #pragma unroll
        for (int w2 = 0; w2 < WPB; ++w2) stot += ls[w2] * __expf(M - lm[w2]);
        ws_m[blockIdx.x] = M;
        ws_s[blockIdx.x] = stot;
    }
}

// Kernel 2: merge K1_BLOCKS partials, produce quantised + losses.
__global__ __launch_bounds__(K2_THREADS) void k_final(
    const float* __restrict__ imu,
    const float* __restrict__ ws_q, const float* __restrict__ ws_m,
    const float* __restrict__ ws_s, float* __restrict__ out)
{
    __shared__ float f_sh[K1_BLOCKS];
    __shared__ float red[8];
    __shared__ float Msh, Ssh;
    const int t = threadIdx.x;
    const int lane = t & 63, wid = t >> 6;

    // global min of block mins (K1_BLOCKS == K2_THREADS == 512)
    float mv = ws_m[t];
    #pragma unroll
    for (int off = 32; off >= 1; off >>= 1) mv = fminf(mv, __shfl_xor(mv, off, 64));
    if (lane == 0) red[wid] = mv;
    __syncthreads();
    if (t == 0) {
        float x = red[0];
        #pragma unroll
        for (int i = 1; i < 8; ++i) x = fminf(x, red[i]);
        Msh = x;
    }
    __syncthreads();
    const float M = Msh;

    // per-block rescale factors + global denominator
    const float f = __expf(M - ws_m[t]);
    f_sh[t] = f;
    float sp = ws_s[t] * f;
    #pragma unroll
    for (int off = 32; off >= 1; off >>= 1) sp += __shfl_xor(sp, off, 64);
    __syncthreads();                       // red[] reuse guard
    if (lane == 0) red[wid] = sp;
    __syncthreads();
    if (t == 0) {
        float x = 0.f;
        #pragma unroll
        for (int i = 0; i < 8; ++i) x += red[i];
        Ssh = x;
    }
    __syncthreads();
    const float S = Ssh;

    // q[t] = sum_b ws_q[b*DIM + t] * f[b]   (coalesced across t)
    float qa = 0.f;
    #pragma unroll 8
    for (int b = 0; b < K1_BLOCKS; ++b) qa += ws_q[b * DIM + t] * f_sh[b];

    const float quant = qa / S;
    out[t] = quant;                        // quantised [0..511]

    // losses: forward values of loss_enc and loss_ref are identical
    const float diff = quant - imu[t];
    float e = diff * diff;
    #pragma unroll
    for (int off = 32; off >= 1; off >>= 1) e += __shfl_xor(e, off, 64);
    __syncthreads();
    if (lane == 0) red[wid] = e;
    __syncthreads();
    if (t == 0) {
        float x = 0.f;
        #pragma unroll
        for (int i = 0; i < 8; ++i) x += red[i];
        x *= (1.0f / DIM);
        out[DIM]     = x;                  // loss_enc
        out[DIM + 1] = x;                  // loss_ref
    }
}

extern "C" void kernel_launch(void* const* d_in, const int* in_sizes, int n_in,
                              void* d_out, int out_size, void* d_ws, size_t ws_size,
                              hipStream_t stream) {
    const float* imu  = (const float*)d_in[0];
    const float* isig = (const float*)d_in[1];
    const float* st   = (const float*)d_in[2];
    float* out = (float*)d_out;
    float* ws  = (float*)d_ws;

    float* ws_q = ws;                       // [K1_BLOCKS][DIM]
    float* ws_m = ws_q + K1_BLOCKS * DIM;   // [K1_BLOCKS]
    float* ws_s = ws_m + K1_BLOCKS;         // [K1_BLOCKS]

    // out layout: quantised [0..511], loss_enc [512], loss_ref [513], dists [514..]
    k_dist<<<K1_BLOCKS, K1_THREADS, 0, stream>>>(imu, isig, st,
                                                 out + DIM + 2, ws_q, ws_m, ws_s);
    k_final<<<1, K2_THREADS, 0, stream>>>(imu, ws_q, ws_m, ws_s, out);
}